// Round 1
// baseline (343.659 us; speedup 1.0000x reference)
//
#include <hip/hip_runtime.h>
#include <hip/hip_bf16.h>
#include <stdint.h>

typedef unsigned short u16;
typedef unsigned int   u32;

#define S_LEN 2048
#define MDIM  2048
#define NQKV  3072
#define NH    32
#define NKV   8
#define DH    64
#define SWIN  128
#define NEGV  (-1.0e9f)
#define SCALE_Q 0.35355339059327379f   // 64^-0.25

typedef __attribute__((ext_vector_type(4)))  float  f32x4;
typedef __attribute__((ext_vector_type(16))) float  f32x16;
typedef __attribute__((ext_vector_type(8)))  __bf16 bf16x8;

__device__ __forceinline__ u16 f2bf(float x){
  u32 u = __float_as_uint(x);
  return (u16)((u + 0x7fffu + ((u >> 16) & 1u)) >> 16);   // RNE
}
__device__ __forceinline__ float bf2f(u16 h){
  return __uint_as_float(((u32)h) << 16);
}
__device__ __forceinline__ void split2(float a, float b, u32& hw, u32& lw){
  u16 ha = f2bf(a), hb = f2bf(b);
  u16 la = f2bf(a - bf2f(ha)), lb = f2bf(b - bf2f(hb));
  hw = (u32)ha | ((u32)hb << 16);
  lw = (u32)la | ((u32)lb << 16);
}
__device__ __forceinline__ f32x4 mfma16(bf16x8 a, bf16x8 b, f32x4 c){
  return __builtin_amdgcn_mfma_f32_16x16x32_bf16(a, b, c, 0, 0, 0);
}
__device__ __forceinline__ f32x16 mfma32(bf16x8 a, bf16x8 b, f32x16 c){
  return __builtin_amdgcn_mfma_f32_32x32x16_bf16(a, b, c, 0, 0, 0);
}

// ---------------- prep: rope table [S][32][(cos,sin)] + packed bias[3072] ----
__global__ __launch_bounds__(256) void k_prep(const float* __restrict__ bq,
                                              const float* __restrict__ bk,
                                              const float* __restrict__ bv,
                                              float* __restrict__ ropetab,
                                              float* __restrict__ bias3){
  int id = blockIdx.x * 256 + threadIdx.x;        // S*32 threads
  int t = id >> 5, i = id & 31;
  float e = (i * 2.0f) / 64.0f;
  float base = (float)pow(150000.0, (double)e);   // match jnp fp32 power to ~ulp
  float invf = 1.0f / base;
  float fr = (float)t * invf;
  ropetab[(size_t)id * 2 + 0] = cosf(fr);
  ropetab[(size_t)id * 2 + 1] = sinf(fr);
  if (id < NQKV){
    float b;
    if (id < 2048) b = bq[id];
    else if (id < 2560) b = bk[id - 2048];
    else b = bv[id - 2560];
    bias3[id] = b;
  }
}

// ---------------- pack A: fp32 [R][C] -> hi/lo bf16 packed [C/8][R][8] -------
__global__ __launch_bounds__(256) void k_pack_a(const float* __restrict__ in,
                                                u16* __restrict__ oh, u16* __restrict__ ol,
                                                int R, int C){
  int id = blockIdx.x * 256 + threadIdx.x;
  int P = C >> 3;
  if (id >= R * P) return;
  int r = id / P, p = id % P;
  const float4* src = (const float4*)(in + (size_t)r * C + p * 8);
  float4 v0 = src[0], v1 = src[1];
  u32 hw[4], lw[4];
  split2(v0.x, v0.y, hw[0], lw[0]);
  split2(v0.z, v0.w, hw[1], lw[1]);
  split2(v1.x, v1.y, hw[2], lw[2]);
  split2(v1.z, v1.w, hw[3], lw[3]);
  size_t o = ((size_t)p * R + r) * 8;
  *(uint4*)(oh + o) = make_uint4(hw[0], hw[1], hw[2], hw[3]);
  *(uint4*)(ol + o) = make_uint4(lw[0], lw[1], lw[2], lw[3]);
}

// ---------------- pack W: fp32 [K][N] (N contig) -> [K/8][NTot][8] at nOff ---
__global__ __launch_bounds__(256) void k_pack_w(const float* __restrict__ w,
                                                u16* __restrict__ oh, u16* __restrict__ ol,
                                                int K, int N, int NTot, int nOff){
  int id = blockIdx.x * 256 + threadIdx.x;
  int P = K >> 3;
  if (id >= P * N) return;
  int p = id / N, n = id % N;
  u32 hw[4], lw[4];
  #pragma unroll
  for (int j = 0; j < 4; ++j){
    float a = w[(size_t)(8 * p + 2 * j) * N + n];
    float b = w[(size_t)(8 * p + 2 * j + 1) * N + n];
    split2(a, b, hw[j], lw[j]);
  }
  size_t o = ((size_t)p * NTot + nOff + n) * 8;
  *(uint4*)(oh + o) = make_uint4(hw[0], hw[1], hw[2], hw[3]);
  *(uint4*)(ol + o) = make_uint4(lw[0], lw[1], lw[2], lw[3]);
}

// ---------------- split-bf16 GEMM: C[M][N] = A*B + bias ---------------------
// A packed [K/8][M][8] hi/lo; B packed [K/8][N][8] hi/lo (i.e. B^T K-packets).
// 128x128 tile, BK=32, 4 waves (2x2), 16x16x32 MFMA, 3 split terms.
__global__ __launch_bounds__(256) void k_gemm(const u16* __restrict__ Ah, const u16* __restrict__ Al,
                                              const u16* __restrict__ Bh, const u16* __restrict__ Bl,
                                              const float* __restrict__ bias, float* __restrict__ C,
                                              int M, int N, int K){
  __shared__ u16 lds[4][4][128][8];   // [tensor: Ah,Al,Bh,Bl][packet][row][8]
  const int tid = threadIdx.x;
  const int lane = tid & 63, wid = tid >> 6;
  const int q = lane & 15, g = lane >> 4;
  const int m0 = blockIdx.y * 128, n0 = blockIdx.x * 128;
  const int wr = wid >> 1, wc = wid & 1;

  f32x4 acc[4][4];
  #pragma unroll
  for (int a = 0; a < 4; ++a)
    #pragma unroll
    for (int b = 0; b < 4; ++b)
      #pragma unroll
      for (int r = 0; r < 4; ++r) acc[a][b][r] = 0.0f;

  const int srow = tid & 127, spb = tid >> 7;  // staging: 2 packets per pass

  for (int k0 = 0; k0 < K; k0 += 32){
    const int pk0 = k0 >> 3;
    #pragma unroll
    for (int c = 0; c < 2; ++c){
      int p = spb + c * 2;
      size_t ga = ((size_t)(pk0 + p) * M + m0 + srow) * 8;
      size_t gb = ((size_t)(pk0 + p) * N + n0 + srow) * 8;
      *(uint4*)&lds[0][p][srow][0] = *(const uint4*)(Ah + ga);
      *(uint4*)&lds[1][p][srow][0] = *(const uint4*)(Al + ga);
      *(uint4*)&lds[2][p][srow][0] = *(const uint4*)(Bh + gb);
      *(uint4*)&lds[3][p][srow][0] = *(const uint4*)(Bl + gb);
    }
    __syncthreads();
    bf16x8 ah[4], al[4], bh[4], bl[4];
    #pragma unroll
    for (int ms = 0; ms < 4; ++ms){
      int row = wr * 64 + ms * 16 + q;
      ah[ms] = *(const bf16x8*)&lds[0][g][row][0];
      al[ms] = *(const bf16x8*)&lds[1][g][row][0];
    }
    #pragma unroll
    for (int ns = 0; ns < 4; ++ns){
      int col = wc * 64 + ns * 16 + q;
      bh[ns] = *(const bf16x8*)&lds[2][g][col][0];
      bl[ns] = *(const bf16x8*)&lds[3][g][col][0];
    }
    #pragma unroll
    for (int ms = 0; ms < 4; ++ms)
      #pragma unroll
      for (int ns = 0; ns < 4; ++ns){
        f32x4 t = acc[ms][ns];
        t = mfma16(ah[ms], bh[ns], t);   // hi*hi
        t = mfma16(ah[ms], bl[ns], t);   // hi*lo
        t = mfma16(al[ms], bh[ns], t);   // lo*hi
        acc[ms][ns] = t;
      }
    __syncthreads();
  }
  #pragma unroll
  for (int ns = 0; ns < 4; ++ns){
    int col = n0 + wc * 64 + ns * 16 + q;
    float bb = bias[col];
    #pragma unroll
    for (int ms = 0; ms < 4; ++ms){
      int row = m0 + wr * 64 + ms * 16 + g * 4;
      #pragma unroll
      for (int r = 0; r < 4; ++r)
        C[(size_t)(row + r) * N + col] = acc[ms][ns][r] + bb;
    }
  }
}

// ---------------- RoPE+scale+split for q: out [NH*8][S][8] hi/lo ------------
__global__ __launch_bounds__(256) void k_rope_q(const float* __restrict__ qkv,
                                                const float* __restrict__ tab,
                                                u16* __restrict__ oh, u16* __restrict__ ol){
  int s = blockIdx.x;
  int t = threadIdx.x;              // t = h*8 + p
  int h = t >> 3, p = t & 7;
  const float* src = qkv + (size_t)s * NQKV + h * 64 + p * 8;
  const float* tb = tab + (size_t)s * 64 + p * 8;
  u32 hw[4], lw[4];
  #pragma unroll
  for (int j = 0; j < 4; ++j){
    float e = src[2 * j], o = src[2 * j + 1];
    float c = tb[2 * j], sn = tb[2 * j + 1];
    float f0 = (e * c - o * sn) * SCALE_Q;
    float f1 = (o * c + e * sn) * SCALE_Q;
    split2(f0, f1, hw[j], lw[j]);
  }
  size_t o_ = ((size_t)t * S_LEN + s) * 8;
  *(uint4*)(oh + o_) = make_uint4(hw[0], hw[1], hw[2], hw[3]);
  *(uint4*)(ol + o_) = make_uint4(lw[0], lw[1], lw[2], lw[3]);
}

// ---------------- RoPE+scale+split for k: out [NKV*8][S][8] hi/lo -----------
__global__ __launch_bounds__(256) void k_rope_k(const float* __restrict__ qkv,
                                                const float* __restrict__ tab,
                                                u16* __restrict__ oh, u16* __restrict__ ol){
  int id = blockIdx.x * 256 + threadIdx.x;   // S*64
  int s = id >> 6; int t = id & 63;
  int h = t >> 3, p = t & 7;
  const float* src = qkv + (size_t)s * NQKV + 2048 + h * 64 + p * 8;
  const float* tb = tab + (size_t)s * 64 + p * 8;
  u32 hw[4], lw[4];
  #pragma unroll
  for (int j = 0; j < 4; ++j){
    float e = src[2 * j], o = src[2 * j + 1];
    float c = tb[2 * j], sn = tb[2 * j + 1];
    float f0 = (e * c - o * sn) * SCALE_Q;
    float f1 = (o * c + e * sn) * SCALE_Q;
    split2(f0, f1, hw[j], lw[j]);
  }
  size_t o_ = ((size_t)t * S_LEN + s) * 8;
  *(uint4*)(oh + o_) = make_uint4(hw[0], hw[1], hw[2], hw[3]);
  *(uint4*)(ol + o_) = make_uint4(lw[0], lw[1], lw[2], lw[3]);
}

// ---------------- split V transposed: out [NKV][S/8][64][8] hi/lo -----------
__global__ __launch_bounds__(256) void k_split_v(const float* __restrict__ qkv,
                                                 u16* __restrict__ oh, u16* __restrict__ ol){
  int id = blockIdx.x * 256 + threadIdx.x;   // NKV*256*64
  int d = id & 63;
  int sp = (id >> 6) & 255;
  int h = id >> 14;
  const float* src = qkv + 2560 + (size_t)h * 64 + d;
  u32 hw[4], lw[4];
  #pragma unroll
  for (int j = 0; j < 4; ++j){
    float a = src[(size_t)(8 * sp + 2 * j) * NQKV];
    float b = src[(size_t)(8 * sp + 2 * j + 1) * NQKV];
    split2(a, b, hw[j], lw[j]);
  }
  size_t o_ = (((size_t)h * 256 + sp) * 64 + d) * 8;
  *(uint4*)(oh + o_) = make_uint4(hw[0], hw[1], hw[2], hw[3]);
  *(uint4*)(ol + o_) = make_uint4(lw[0], lw[1], lw[2], lw[3]);
}

// ---------------- banded attention with sink (flash, swapped QK^T) ----------
// grid (NH, S/128), 256 thr = 4 waves, wave = 32 q rows.
// scores^T via mfma(K, Q): acc col = q (lane&31), row = key-in-tile.
// output written directly as split-bf16 packed [256][S][8] for the final GEMM.
__global__ __launch_bounds__(256) void k_attn(const u16* __restrict__ qh, const u16* __restrict__ ql,
                                              const u16* __restrict__ kh, const u16* __restrict__ kl,
                                              const u16* __restrict__ vh, const u16* __restrict__ vl,
                                              const float* __restrict__ sinks,
                                              u16* __restrict__ aoh, u16* __restrict__ aol){
  const int lane = threadIdx.x & 63;
  const int wid = threadIdx.x >> 6;
  const int h = blockIdx.x;
  const int hkv = h >> 2;
  const int q0 = blockIdx.y * 128 + wid * 32;
  const int lq = lane & 31;
  const int half = lane >> 5;
  const int qi = q0 + lq;

  // Q fragments (B operand of swapped QK^T): packet = st*2 + half
  bf16x8 qfh[4], qfl[4];
  #pragma unroll
  for (int st = 0; st < 4; ++st){
    size_t off = (((size_t)h * 8 + st * 2 + half) * S_LEN + qi) * 8;
    qfh[st] = *(const bf16x8*)(qh + off);
    qfl[st] = *(const bf16x8*)(ql + off);
  }
  float m = sinks[h];       // fold sink into online softmax: m0=sink, l0=exp(0)=1
  float lsum = 1.0f;
  f32x16 o0, o1;
  #pragma unroll
  for (int r = 0; r < 16; ++r){ o0[r] = 0.0f; o1[r] = 0.0f; }

  const int kb0 = q0 - 128;
  for (int c = 0; c < 9; ++c){
    const int kb = kb0 + c * 32;
    if (kb + 32 <= 0 || kb >= S_LEN) continue;   // wave-uniform skip
    const int keyr = kb + lq;
    const int keyc = min(max(keyr, 0), S_LEN - 1);  // clamp: garbage stays finite, masked later
    f32x16 sc;
    #pragma unroll
    for (int r = 0; r < 16; ++r) sc[r] = 0.0f;
    #pragma unroll
    for (int st = 0; st < 4; ++st){
      size_t ko = (((size_t)hkv * 8 + st * 2 + half) * S_LEN + keyc) * 8;
      bf16x8 kfh = *(const bf16x8*)(kh + ko);
      bf16x8 kfl = *(const bf16x8*)(kl + ko);
      sc = mfma32(kfh, qfh[st], sc);
      sc = mfma32(kfh, qfl[st], sc);
      sc = mfma32(kfl, qfh[st], sc);
    }
    // mask (|q-k|<=SW, in-range) + tile max
    float tmax = -3.0e38f;
    #pragma unroll
    for (int r = 0; r < 16; ++r){
      int key = kb + (r & 3) + 8 * (r >> 2) + 4 * half;
      int dd = qi - key; if (dd < 0) dd = -dd;
      bool ok = (key >= 0) && (key < S_LEN) && (dd <= SWIN);
      sc[r] = ok ? sc[r] : NEGV;
      tmax = fmaxf(tmax, sc[r]);
    }
    tmax = fmaxf(tmax, __shfl_xor(tmax, 32));
    float mn = fmaxf(m, tmax);
    float alpha = __expf(m - mn);
    m = mn;
    float p[16]; float ps = 0.0f;
    #pragma unroll
    for (int r = 0; r < 16; ++r){ p[r] = __expf(sc[r] - mn); ps += p[r]; }
    ps += __shfl_xor(ps, 32);
    lsum = lsum * alpha + ps;
    #pragma unroll
    for (int r = 0; r < 16; ++r){ o0[r] *= alpha; o1[r] *= alpha; }
    // split P and build PV B-fragments (P^T): half-exchange via shfl_xor 32
    u32 wh[8], wl[8];
    #pragma unroll
    for (int j = 0; j < 8; ++j) split2(p[2 * j], p[2 * j + 1], wh[j], wl[j]);
    bf16x8 pfh[2], pfl[2];
    #pragma unroll
    for (int ks = 0; ks < 2; ++ks){
      u32 x0 = wh[4 * ks + 0], y0 = wh[4 * ks + 2];
      u32 x1 = wh[4 * ks + 1], y1 = wh[4 * ks + 3];
      u32 sx0 = __shfl_xor(x0, 32), sy0 = __shfl_xor(y0, 32);
      u32 sx1 = __shfl_xor(x1, 32), sy1 = __shfl_xor(y1, 32);
      union { u32 u[4]; bf16x8 b; } fb;
      fb.u[0] = half ? sy0 : x0;
      fb.u[1] = half ? sy1 : x1;
      fb.u[2] = half ? y0 : sx0;
      fb.u[3] = half ? y1 : sx1;
      pfh[ks] = fb.b;
      u32 a0 = wl[4 * ks + 0], b0 = wl[4 * ks + 2];
      u32 a1 = wl[4 * ks + 1], b1 = wl[4 * ks + 3];
      u32 sa0 = __shfl_xor(a0, 32), sb0 = __shfl_xor(b0, 32);
      u32 sa1 = __shfl_xor(a1, 32), sb1 = __shfl_xor(b1, 32);
      fb.u[0] = half ? sb0 : a0;
      fb.u[1] = half ? sb1 : a1;
      fb.u[2] = half ? b0 : sa0;
      fb.u[3] = half ? b1 : sa1;
      pfl[ks] = fb.b;
    }
    // PV: out^T = V^T * P^T  (A = V^T frag, B = P frag); acc col=q, row=d
    #pragma unroll
    for (int ks = 0; ks < 2; ++ks){
      int kp = kb / 8 + ks * 2 + half;
      kp = min(max(kp, 0), S_LEN / 8 - 1);
      #pragma unroll
      for (int nt = 0; nt < 2; ++nt){
        size_t vo = (((size_t)hkv * 256 + kp) * 64 + nt * 32 + lq) * 8;
        bf16x8 vfh = *(const bf16x8*)(vh + vo);
        bf16x8 vfl = *(const bf16x8*)(vl + vo);
        f32x16 acc = (nt == 0) ? o0 : o1;
        acc = mfma32(vfh, pfh[ks], acc);
        acc = mfma32(vfh, pfl[ks], acc);
        acc = mfma32(vfl, pfh[ks], acc);
        if (nt == 0) o0 = acc; else o1 = acc;
      }
    }
  }
  // epilogue: normalize, split hi/lo, write packed [(h*64+d)/8][s][d%8]
  float inv = 1.0f / lsum;
  #pragma unroll
  for (int nt = 0; nt < 2; ++nt){
    f32x16 o = (nt == 0) ? o0 : o1;
    #pragma unroll
    for (int rr = 0; rr < 4; ++rr){
      int d0 = nt * 32 + 8 * rr + 4 * half;
      u32 hw0, hw1, lw0, lw1;
      float v0 = o[rr * 4 + 0] * inv, v1 = o[rr * 4 + 1] * inv;
      float v2 = o[rr * 4 + 2] * inv, v3 = o[rr * 4 + 3] * inv;
      split2(v0, v1, hw0, lw0);
      split2(v2, v3, hw1, lw1);
      int kp_ = h * 8 + nt * 4 + rr;
      size_t oo = ((size_t)kp_ * S_LEN + qi) * 8 + (d0 & 7);
      uint2 wv; wv.x = hw0; wv.y = hw1;
      *(uint2*)(aoh + oo) = wv;
      wv.x = lw0; wv.y = lw1;
      *(uint2*)(aol + oo) = wv;
    }
  }
}

// ---------------------------------------------------------------------------
extern "C" void kernel_launch(void* const* d_in, const int* in_sizes, int n_in,
                              void* d_out, int out_size, void* d_ws, size_t ws_size,
                              hipStream_t stream){
  const float* hid = (const float*)d_in[0];
  const float* Wq  = (const float*)d_in[1];
  const float* bq  = (const float*)d_in[2];
  const float* Wk  = (const float*)d_in[3];
  const float* bk  = (const float*)d_in[4];
  const float* Wv  = (const float*)d_in[5];
  const float* bv  = (const float*)d_in[6];
  const float* Wo  = (const float*)d_in[7];
  const float* bo  = (const float*)d_in[8];
  const float* sinks = (const float*)d_in[9];
  float* out = (float*)d_out;

  char* w = (char*)d_ws;
  size_t off = 0;
  auto alloc = [&](size_t bytes){ void* p = w + off; off += (bytes + 255) & ~(size_t)255; return p; };
  float* ropetab = (float*)alloc((size_t)S_LEN * 32 * 2 * 4);      // 0.5 MB
  float* bias3   = (float*)alloc((size_t)NQKV * 4);
  u16* Ah  = (u16*)alloc((size_t)256 * 2048 * 8 * 2);              // hidden packed
  u16* Al  = (u16*)alloc((size_t)256 * 2048 * 8 * 2);
  u16* Bh  = (u16*)alloc((size_t)256 * NQKV * 8 * 2);              // Wq|Wk|Wv packed
  u16* Bl  = (u16*)alloc((size_t)256 * NQKV * 8 * 2);
  float* QKV = (float*)alloc((size_t)S_LEN * NQKV * 4);            // 25 MB
  u16* qph = (u16*)alloc((size_t)NH * 8 * S_LEN * 8 * 2);
  u16* qpl = (u16*)alloc((size_t)NH * 8 * S_LEN * 8 * 2);
  u16* kph = (u16*)alloc((size_t)NKV * 8 * S_LEN * 8 * 2);
  u16* kpl = (u16*)alloc((size_t)NKV * 8 * S_LEN * 8 * 2);
  u16* vph = (u16*)alloc((size_t)NKV * 256 * 64 * 8 * 2);
  u16* vpl = (u16*)alloc((size_t)NKV * 256 * 64 * 8 * 2);
  u16* aoh = (u16*)alloc((size_t)256 * S_LEN * 8 * 2);             // attn out packed
  u16* aol = (u16*)alloc((size_t)256 * S_LEN * 8 * 2);
  u16* Woh = (u16*)alloc((size_t)256 * 2048 * 8 * 2);
  u16* Wol = (u16*)alloc((size_t)256 * 2048 * 8 * 2);
  // total ~127 MB
  (void)in_sizes; (void)n_in; (void)out_size; (void)ws_size;

  k_prep<<<256, 256, 0, stream>>>(bq, bk, bv, ropetab, bias3);
  k_pack_a<<<(2048 * 256) / 256, 256, 0, stream>>>(hid, Ah, Al, 2048, 2048);
  k_pack_w<<<(256 * 2048) / 256, 256, 0, stream>>>(Wq, Bh, Bl, 2048, 2048, NQKV, 0);
  k_pack_w<<<(256 * 512) / 256, 256, 0, stream>>>(Wk, Bh, Bl, 2048, 512, NQKV, 2048);
  k_pack_w<<<(256 * 512) / 256, 256, 0, stream>>>(Wv, Bh, Bl, 2048, 512, NQKV, 2560);
  k_pack_w<<<(256 * 2048) / 256, 256, 0, stream>>>(Wo, Woh, Wol, 2048, 2048, 2048, 0);
  k_gemm<<<dim3(NQKV / 128, 2048 / 128), 256, 0, stream>>>(Ah, Al, Bh, Bl, bias3, QKV,
                                                           2048, NQKV, 2048);
  k_rope_q<<<S_LEN, 256, 0, stream>>>(QKV, ropetab, qph, qpl);
  k_rope_k<<<(S_LEN * 64) / 256, 256, 0, stream>>>(QKV, ropetab, kph, kpl);
  k_split_v<<<(NKV * 256 * 64) / 256, 256, 0, stream>>>(QKV, vph, vpl);
  k_attn<<<dim3(NH, S_LEN / 128), 256, 0, stream>>>(qph, qpl, kph, kpl, vph, vpl, sinks, aoh, aol);
  k_gemm<<<dim3(2048 / 128, 2048 / 128), 256, 0, stream>>>(aoh, aol, Woh, Wol, bo, out,
                                                           2048, 2048, 2048);
}

// Round 3
// 304.992 us; speedup vs baseline: 1.1268x; 1.1268x over previous
//
#include <hip/hip_runtime.h>
#include <hip/hip_bf16.h>
#include <stdint.h>

typedef unsigned short u16;
typedef unsigned int   u32;

#define S_LEN 2048
#define NQKV  3072
#define NH    32
#define NKV   8
#define SWIN  128
#define NEGV  (-1.0e9f)
#define SCALE_Q 0.35355339059327379f   // 64^-0.25

typedef __attribute__((ext_vector_type(4)))  float  f32x4;
typedef __attribute__((ext_vector_type(16))) float  f32x16;
typedef __attribute__((ext_vector_type(8)))  __bf16 bf16x8;

__device__ __forceinline__ u16 f2bf(float x){
  u32 u = __float_as_uint(x);
  return (u16)((u + 0x7fffu + ((u >> 16) & 1u)) >> 16);   // RNE
}
__device__ __forceinline__ float bf2f(u16 h){
  return __uint_as_float(((u32)h) << 16);
}
__device__ __forceinline__ void split2(float a, float b, u32& hw, u32& lw){
  u16 ha = f2bf(a), hb = f2bf(b);
  u16 la = f2bf(a - bf2f(ha)), lb = f2bf(b - bf2f(hb));
  hw = (u32)ha | ((u32)hb << 16);
  lw = (u32)la | ((u32)lb << 16);
}
__device__ __forceinline__ f32x4 mfma16(bf16x8 a, bf16x8 b, f32x4 c){
  return __builtin_amdgcn_mfma_f32_16x16x32_bf16(a, b, c, 0, 0, 0);
}
__device__ __forceinline__ f32x16 mfma32(bf16x8 a, bf16x8 b, f32x16 c){
  return __builtin_amdgcn_mfma_f32_32x32x16_bf16(a, b, c, 0, 0, 0);
}

typedef __attribute__((address_space(1))) const unsigned int ga_u32;
typedef __attribute__((address_space(3))) unsigned int       ls_u32;
__device__ __forceinline__ void gl16(const void* g, void* l){
  // direct global->LDS, 16B per lane; LDS dest = wave-uniform base + lane*16
  __builtin_amdgcn_global_load_lds((ga_u32*)g, (ls_u32*)l, 16, 0, 0);
}

// ---------------- prep: rope table [S][32][(cos,sin)] + packed bias[3072] ----
__global__ __launch_bounds__(256) void k_prep(const float* __restrict__ bq,
                                              const float* __restrict__ bk,
                                              const float* __restrict__ bv,
                                              float* __restrict__ ropetab,
                                              float* __restrict__ bias3){
  int id = blockIdx.x * 256 + threadIdx.x;        // S*32 threads
  int t = id >> 5, i = id & 31;
  float e = (i * 2.0f) / 64.0f;
  float base = (float)pow(150000.0, (double)e);
  float invf = 1.0f / base;
  float fr = (float)t * invf;
  ropetab[(size_t)id * 2 + 0] = cosf(fr);
  ropetab[(size_t)id * 2 + 1] = sinf(fr);
  if (id < NQKV){
    float b;
    if (id < 2048) b = bq[id];
    else if (id < 2560) b = bk[id - 2048];
    else b = bv[id - 2560];
    bias3[id] = b;
  }
}

// ---------------- pack A streaming: fp32 row-major -> hi/lo bf16 [M][K/8][8] -
__global__ __launch_bounds__(256) void k_pack_a(const float* __restrict__ in,
                                                u16* __restrict__ oh, u16* __restrict__ ol,
                                                int n8){
  int id = blockIdx.x * 256 + threadIdx.x;
  if (id >= n8) return;
  const float4* src = (const float4*)(in + (size_t)id * 8);
  float4 v0 = src[0], v1 = src[1];
  u32 hw[4], lw[4];
  split2(v0.x, v0.y, hw[0], lw[0]);
  split2(v0.z, v0.w, hw[1], lw[1]);
  split2(v1.x, v1.y, hw[2], lw[2]);
  split2(v1.z, v1.w, hw[3], lw[3]);
  size_t o = (size_t)id * 8;
  *(uint4*)(oh + o) = make_uint4(hw[0], hw[1], hw[2], hw[3]);
  *(uint4*)(ol + o) = make_uint4(lw[0], lw[1], lw[2], lw[3]);
}

// ---------------- pack W: fp32 [K][N] (N contig) -> [K/8][NTot][8] at nOff ---
__global__ __launch_bounds__(256) void k_pack_w(const float* __restrict__ w,
                                                u16* __restrict__ oh, u16* __restrict__ ol,
                                                int K, int N, int NTot, int nOff){
  int id = blockIdx.x * 256 + threadIdx.x;
  int P = K >> 3;
  if (id >= P * N) return;
  int p = id / N, n = id % N;
  u32 hw[4], lw[4];
  #pragma unroll
  for (int j = 0; j < 4; ++j){
    float a = w[(size_t)(8 * p + 2 * j) * N + n];
    float b = w[(size_t)(8 * p + 2 * j + 1) * N + n];
    split2(a, b, hw[j], lw[j]);
  }
  size_t o = ((size_t)p * NTot + nOff + n) * 8;
  *(uint4*)(oh + o) = make_uint4(hw[0], hw[1], hw[2], hw[3]);
  *(uint4*)(ol + o) = make_uint4(lw[0], lw[1], lw[2], lw[3]);
}

// ---------------- split-bf16 GEMM v2: dbuf + global_load_lds, 2-phase -------
// ARM=true : A packed [M][K/8][8] (streaming layout)
// ARM=false: A packed [K/8][M][8] (attn-output layout)
// B packed [K/8][N][8]. 128x128 tile, BK=32, 4 waves (2x2), 16x16x32 MFMA,
// 3 split terms. T3-minimum 2-phase: STAGE(t+1) -> compute(t) -> syncthreads.
template<bool ARM>
__global__ __launch_bounds__(256, 2) void k_gemm2(const u16* __restrict__ Ah, const u16* __restrict__ Al,
                                                  const u16* __restrict__ Bh, const u16* __restrict__ Bl,
                                                  const float* __restrict__ bias, float* __restrict__ C,
                                                  int M, int N, int K){
  __shared__ u16 lds[2][4][512][8];   // 64 KiB: [buf][tensor Ah,Al,Bh,Bl][packet][8]
  const int tid = threadIdx.x;
  const int lane = tid & 63, wid = tid >> 6;
  const int q = lane & 15, g = lane >> 4;
  const int m0 = blockIdx.y * 128, n0 = blockIdx.x * 128;
  const int wr = wid >> 1, wc = wid & 1;
  const int pkK = K >> 3;

  f32x4 acc[4][4];
  #pragma unroll
  for (int a = 0; a < 4; ++a)
    #pragma unroll
    for (int b = 0; b < 4; ++b)
      #pragma unroll
      for (int r = 0; r < 4; ++r) acc[a][b][r] = 0.0f;

  size_t aoff[2], boff[2];
  #pragma unroll
  for (int c = 0; c < 2; ++c){
    int L = c * 256 + tid;
    if (ARM){
      int row = L >> 2, pa = L & 3;
      aoff[c] = ((size_t)(m0 + row) * pkK + pa) * 8;
    } else {
      int pa = L >> 7, row = L & 127;
      aoff[c] = ((size_t)pa * M + m0 + row) * 8;
    }
    int pb = L >> 7, col = L & 127;
    boff[c] = ((size_t)pb * N + n0 + col) * 8;
  }
  const size_t astep = ARM ? (size_t)32 : (size_t)32 * M;   // +4 packets per K-step
  const size_t bstep = (size_t)32 * N;

  const int NT = K >> 5;
  int buf = 0;

  auto STAGE = [&](int b){
    #pragma unroll
    for (int c = 0; c < 2; ++c){
      int lbase = c * 256 + wid * 64;   // wave-uniform LDS packet base
      gl16(Ah + aoff[c], &lds[b][0][lbase][0]);
      gl16(Al + aoff[c], &lds[b][1][lbase][0]);
      gl16(Bh + boff[c], &lds[b][2][lbase][0]);
      gl16(Bl + boff[c], &lds[b][3][lbase][0]);
    }
    aoff[0] += astep; aoff[1] += astep;
    boff[0] += bstep; boff[1] += bstep;
  };

  STAGE(0);
  __syncthreads();

  for (int t = 0; t < NT; ++t){
    if (t + 1 < NT) STAGE(buf ^ 1);   // issue-early: latency hides under MFMA
    bf16x8 ah[4], al[4], bh[4], bl[4];
    #pragma unroll
    for (int ms = 0; ms < 4; ++ms){
      int row = wr * 64 + ms * 16 + q;
      int ia = ARM ? (row * 4 + g) : (g * 128 + row);
      ah[ms] = *(const bf16x8*)&lds[buf][0][ia][0];
      al[ms] = *(const bf16x8*)&lds[buf][1][ia][0];
    }
    #pragma unroll
    for (int ns = 0; ns < 4; ++ns){
      int col = wc * 64 + ns * 16 + q;
      int ib = g * 128 + col;
      bh[ns] = *(const bf16x8*)&lds[buf][2][ib][0];
      bl[ns] = *(const bf16x8*)&lds[buf][3][ib][0];
    }
    #pragma unroll
    for (int ms = 0; ms < 4; ++ms)
      #pragma unroll
      for (int ns = 0; ns < 4; ++ns){
        f32x4 tt = acc[ms][ns];
        tt = mfma16(ah[ms], bh[ns], tt);   // hi*hi
        tt = mfma16(ah[ms], bl[ns], tt);   // hi*lo
        tt = mfma16(al[ms], bh[ns], tt);   // lo*hi
        acc[ms][ns] = tt;
      }
    __syncthreads();   // vmcnt(0)+lgkmcnt(0)+barrier: next buf ready, this buf free
    buf ^= 1;
  }

  #pragma unroll
  for (int ns = 0; ns < 4; ++ns){
    int col = n0 + wc * 64 + ns * 16 + q;
    float bb = bias[col];
    #pragma unroll
    for (int ms = 0; ms < 4; ++ms){
      int row = m0 + wr * 64 + ms * 16 + g * 4;
      #pragma unroll
      for (int r = 0; r < 4; ++r)
        C[(size_t)(row + r) * N + col] = acc[ms][ns][r] + bb;
    }
  }
}

// ---------------- RoPE+scale+split q: out [NH*8][S][8], coalesced both sides
// grid (S/64, NH); wave tp handles dims [tp*16, tp*16+16), lane = s within chunk
__global__ __launch_bounds__(256) void k_rope_q2(const float* __restrict__ qkv,
                                                 const float* __restrict__ tab,
                                                 u16* __restrict__ oh, u16* __restrict__ ol,
                                                 int srcOff, int hTot){
  const int sL = threadIdx.x & 63, tp = threadIdx.x >> 6;
  const int s = blockIdx.x * 64 + sL;
  const int h = blockIdx.y;
  const float4* src = (const float4*)(qkv + (size_t)s * NQKV + srcOff + h * 64 + tp * 16);
  const float4* tb  = (const float4*)(tab + (size_t)s * 64 + tp * 16);
  float xv[16], tv[16];
  #pragma unroll
  for (int i = 0; i < 4; ++i){
    float4 a = src[i]; float4 b = tb[i];
    xv[4*i+0]=a.x; xv[4*i+1]=a.y; xv[4*i+2]=a.z; xv[4*i+3]=a.w;
    tv[4*i+0]=b.x; tv[4*i+1]=b.y; tv[4*i+2]=b.z; tv[4*i+3]=b.w;
  }
  u32 hw[8], lw[8];
  #pragma unroll
  for (int j = 0; j < 8; ++j){
    float e = xv[2*j], o = xv[2*j+1];
    float c = tv[2*j], sn = tv[2*j+1];
    float f0 = (e * c - o * sn) * SCALE_Q;
    float f1 = (o * c + e * sn) * SCALE_Q;
    split2(f0, f1, hw[j], lw[j]);
  }
  (void)hTot;
  size_t o0 = ((size_t)(h * 8 + tp * 2 + 0) * S_LEN + s) * 8;
  size_t o1 = ((size_t)(h * 8 + tp * 2 + 1) * S_LEN + s) * 8;
  *(uint4*)(oh + o0) = make_uint4(hw[0], hw[1], hw[2], hw[3]);
  *(uint4*)(oh + o1) = make_uint4(hw[4], hw[5], hw[6], hw[7]);
  *(uint4*)(ol + o0) = make_uint4(lw[0], lw[1], lw[2], lw[3]);
  *(uint4*)(ol + o1) = make_uint4(lw[4], lw[5], lw[6], lw[7]);
}

// ---------------- split V transposed: out [NKV][S/8][64][8], LDS-bounced ----
// grid (S/64, NKV)
__global__ __launch_bounds__(256) void k_split_v2(const float* __restrict__ qkv,
                                                  u16* __restrict__ oh, u16* __restrict__ ol){
  __shared__ float tile[64][65];
  const int h = blockIdx.y;
  const int s0 = blockIdx.x * 64;
  {
    const int sL = threadIdx.x >> 2, ch = threadIdx.x & 3;
    const float4* rp = (const float4*)(qkv + (size_t)(s0 + sL) * NQKV + 2560 + h * 64 + ch * 16);
    #pragma unroll
    for (int i = 0; i < 4; ++i){
      float4 w = rp[i];
      tile[sL][ch * 16 + i * 4 + 0] = w.x;
      tile[sL][ch * 16 + i * 4 + 1] = w.y;
      tile[sL][ch * 16 + i * 4 + 2] = w.z;
      tile[sL][ch * 16 + i * 4 + 3] = w.w;
    }
  }
  __syncthreads();
  const int d = threadIdx.x & 63, spg = threadIdx.x >> 6;
  #pragma unroll
  for (int sp2 = 0; sp2 < 2; ++sp2){
    int spl = spg * 2 + sp2;
    float v[8];
    #pragma unroll
    for (int j = 0; j < 8; ++j) v[j] = tile[spl * 8 + j][d];
    u32 hw[4], lw[4];
    #pragma unroll
    for (int j = 0; j < 4; ++j) split2(v[2*j], v[2*j+1], hw[j], lw[j]);
    size_t o_ = (((size_t)h * 256 + blockIdx.x * 8 + spl) * 64 + d) * 8;
    *(uint4*)(oh + o_) = make_uint4(hw[0], hw[1], hw[2], hw[3]);
    *(uint4*)(ol + o_) = make_uint4(lw[0], lw[1], lw[2], lw[3]);
  }
}

// ---------------- banded attention with sink (flash, swapped QK^T) ----------
__global__ __launch_bounds__(256) void k_attn(const u16* __restrict__ qh, const u16* __restrict__ ql,
                                              const u16* __restrict__ kh, const u16* __restrict__ kl,
                                              const u16* __restrict__ vh, const u16* __restrict__ vl,
                                              const float* __restrict__ sinks,
                                              u16* __restrict__ aoh, u16* __restrict__ aol){
  const int lane = threadIdx.x & 63;
  const int wid = threadIdx.x >> 6;
  const int h = blockIdx.x;
  const int hkv = h >> 2;
  const int q0 = blockIdx.y * 128 + wid * 32;
  const int lq = lane & 31;
  const int half = lane >> 5;
  const int qi = q0 + lq;

  bf16x8 qfh[4], qfl[4];
  #pragma unroll
  for (int st = 0; st < 4; ++st){
    size_t off = (((size_t)h * 8 + st * 2 + half) * S_LEN + qi) * 8;
    qfh[st] = *(const bf16x8*)(qh + off);
    qfl[st] = *(const bf16x8*)(ql + off);
  }
  float m = sinks[h];
  float lsum = 1.0f;
  f32x16 o0, o1;
  #pragma unroll
  for (int r = 0; r < 16; ++r){ o0[r] = 0.0f; o1[r] = 0.0f; }

  const int kb0 = q0 - 128;
  for (int c = 0; c < 9; ++c){
    const int kb = kb0 + c * 32;
    if (kb + 32 <= 0 || kb >= S_LEN) continue;
    const int keyr = kb + lq;
    const int keyc = min(max(keyr, 0), S_LEN - 1);
    f32x16 sc;
    #pragma unroll
    for (int r = 0; r < 16; ++r) sc[r] = 0.0f;
    #pragma unroll
    for (int st = 0; st < 4; ++st){
      size_t ko = (((size_t)hkv * 8 + st * 2 + half) * S_LEN + keyc) * 8;
      bf16x8 kfh = *(const bf16x8*)(kh + ko);
      bf16x8 kfl = *(const bf16x8*)(kl + ko);
      sc = mfma32(kfh, qfh[st], sc);
      sc = mfma32(kfh, qfl[st], sc);
      sc = mfma32(kfl, qfh[st], sc);
    }
    float tmax = -3.0e38f;
    #pragma unroll
    for (int r = 0; r < 16; ++r){
      int key = kb + (r & 3) + 8 * (r >> 2) + 4 * half;
      int dd = qi - key; if (dd < 0) dd = -dd;
      bool ok = (key >= 0) && (key < S_LEN) && (dd <= SWIN);
      sc[r] = ok ? sc[r] : NEGV;
      tmax = fmaxf(tmax, sc[r]);
    }
    tmax = fmaxf(tmax, __shfl_xor(tmax, 32));
    float mn = fmaxf(m, tmax);
    float alpha = __expf(m - mn);
    m = mn;
    float p[16]; float ps = 0.0f;
    #pragma unroll
    for (int r = 0; r < 16; ++r){ p[r] = __expf(sc[r] - mn); ps += p[r]; }
    ps += __shfl_xor(ps, 32);
    lsum = lsum * alpha + ps;
    #pragma unroll
    for (int r = 0; r < 16; ++r){ o0[r] *= alpha; o1[r] *= alpha; }
    u32 wh[8], wl[8];
    #pragma unroll
    for (int j = 0; j < 8; ++j) split2(p[2 * j], p[2 * j + 1], wh[j], wl[j]);
    bf16x8 pfh[2], pfl[2];
    #pragma unroll
    for (int ks = 0; ks < 2; ++ks){
      u32 x0 = wh[4 * ks + 0], y0 = wh[4 * ks + 2];
      u32 x1 = wh[4 * ks + 1], y1 = wh[4 * ks + 3];
      u32 sx0 = __shfl_xor(x0, 32), sy0 = __shfl_xor(y0, 32);
      u32 sx1 = __shfl_xor(x1, 32), sy1 = __shfl_xor(y1, 32);
      union { u32 u[4]; bf16x8 b; } fb;
      fb.u[0] = half ? sy0 : x0;
      fb.u[1] = half ? sy1 : x1;
      fb.u[2] = half ? y0 : sx0;
      fb.u[3] = half ? y1 : sx1;
      pfh[ks] = fb.b;
      u32 a0 = wl[4 * ks + 0], b0 = wl[4 * ks + 2];
      u32 a1 = wl[4 * ks + 1], b1 = wl[4 * ks + 3];
      u32 sa0 = __shfl_xor(a0, 32), sb0 = __shfl_xor(b0, 32);
      u32 sa1 = __shfl_xor(a1, 32), sb1 = __shfl_xor(b1, 32);
      fb.u[0] = half ? sb0 : a0;
      fb.u[1] = half ? sb1 : a1;
      fb.u[2] = half ? b0 : sa0;
      fb.u[3] = half ? b1 : sa1;
      pfl[ks] = fb.b;
    }
    #pragma unroll
    for (int ks = 0; ks < 2; ++ks){
      int kp = kb / 8 + ks * 2 + half;
      kp = min(max(kp, 0), S_LEN / 8 - 1);
      #pragma unroll
      for (int nt = 0; nt < 2; ++nt){
        size_t vo = (((size_t)hkv * 256 + kp) * 64 + nt * 32 + lq) * 8;
        bf16x8 vfh = *(const bf16x8*)(vh + vo);
        bf16x8 vfl = *(const bf16x8*)(vl + vo);
        f32x16 acc = (nt == 0) ? o0 : o1;
        acc = mfma32(vfh, pfh[ks], acc);
        acc = mfma32(vfh, pfl[ks], acc);
        acc = mfma32(vfl, pfh[ks], acc);
        if (nt == 0) o0 = acc; else o1 = acc;
      }
    }
  }
  float inv = 1.0f / lsum;
  #pragma unroll
  for (int nt = 0; nt < 2; ++nt){
    f32x16 o = (nt == 0) ? o0 : o1;
    #pragma unroll
    for (int rr = 0; rr < 4; ++rr){
      int d0 = nt * 32 + 8 * rr + 4 * half;
      u32 hw0, hw1, lw0, lw1;
      float v0 = o[rr * 4 + 0] * inv, v1 = o[rr * 4 + 1] * inv;
      float v2 = o[rr * 4 + 2] * inv, v3 = o[rr * 4 + 3] * inv;
      split2(v0, v1, hw0, lw0);
      split2(v2, v3, hw1, lw1);
      int kp_ = h * 8 + nt * 4 + rr;
      size_t oo = ((size_t)kp_ * S_LEN + qi) * 8 + (d0 & 7);
      uint2 wv; wv.x = hw0; wv.y = hw1;
      *(uint2*)(aoh + oo) = wv;
      wv.x = lw0; wv.y = lw1;
      *(uint2*)(aol + oo) = wv;
    }
  }
}

// ---------------------------------------------------------------------------
extern "C" void kernel_launch(void* const* d_in, const int* in_sizes, int n_in,
                              void* d_out, int out_size, void* d_ws, size_t ws_size,
                              hipStream_t stream){
  const float* hid = (const float*)d_in[0];
  const float* Wq  = (const float*)d_in[1];
  const float* bq  = (const float*)d_in[2];
  const float* Wk  = (const float*)d_in[3];
  const float* bk  = (const float*)d_in[4];
  const float* Wv  = (const float*)d_in[5];
  const float* bv  = (const float*)d_in[6];
  const float* Wo  = (const float*)d_in[7];
  const float* bo  = (const float*)d_in[8];
  const float* sinks = (const float*)d_in[9];
  float* out = (float*)d_out;

  char* w = (char*)d_ws;
  size_t off = 0;
  auto alloc = [&](size_t bytes){ void* p = w + off; off += (bytes + 255) & ~(size_t)255; return p; };
  float* ropetab = (float*)alloc((size_t)S_LEN * 32 * 2 * 4);
  float* bias3   = (float*)alloc((size_t)NQKV * 4);
  u16* Ah  = (u16*)alloc((size_t)2048 * 2048 * 2);        // hidden packed [M][K/8][8]
  u16* Al  = (u16*)alloc((size_t)2048 * 2048 * 2);
  u16* Bh  = (u16*)alloc((size_t)256 * NQKV * 8 * 2);     // Wq|Wk|Wv packed [K/8][N][8]
  u16* Bl  = (u16*)alloc((size_t)256 * NQKV * 8 * 2);
  float* QKV = (float*)alloc((size_t)S_LEN * NQKV * 4);
  u16* qph = (u16*)alloc((size_t)NH * 8 * S_LEN * 8 * 2);
  u16* qpl = (u16*)alloc((size_t)NH * 8 * S_LEN * 8 * 2);
  u16* kph = (u16*)alloc((size_t)NKV * 8 * S_LEN * 8 * 2);
  u16* kpl = (u16*)alloc((size_t)NKV * 8 * S_LEN * 8 * 2);
  u16* vph = (u16*)alloc((size_t)NKV * 256 * 64 * 8 * 2);
  u16* vpl = (u16*)alloc((size_t)NKV * 256 * 64 * 8 * 2);
  u16* aoh = (u16*)alloc((size_t)256 * S_LEN * 8 * 2);    // attn out [K/8][S][8]
  u16* aol = (u16*)alloc((size_t)256 * S_LEN * 8 * 2);
  u16* Woh = (u16*)alloc((size_t)256 * 2048 * 8 * 2);
  u16* Wol = (u16*)alloc((size_t)256 * 2048 * 8 * 2);
  (void)in_sizes; (void)n_in; (void)out_size; (void)ws_size;

  k_prep<<<256, 256, 0, stream>>>(bq, bk, bv, ropetab, bias3);
  k_pack_a<<<2048, 256, 0, stream>>>(hid, Ah, Al, 2048 * 256);
  k_pack_w<<<2048, 256, 0, stream>>>(Wq, Bh, Bl, 2048, 2048, NQKV, 0);
  k_pack_w<<<512, 256, 0, stream>>>(Wk, Bh, Bl, 2048, 512, NQKV, 2048);
  k_pack_w<<<512, 256, 0, stream>>>(Wv, Bh, Bl, 2048, 512, NQKV, 2560);
  k_pack_w<<<2048, 256, 0, stream>>>(Wo, Woh, Wol, 2048, 2048, 2048, 0);
  k_gemm2<true><<<dim3(NQKV / 128, 2048 / 128), 256, 0, stream>>>(Ah, Al, Bh, Bl, bias3, QKV,
                                                                  2048, NQKV, 2048);
  k_rope_q2<<<dim3(32, NH), 256, 0, stream>>>(QKV, ropetab, qph, qpl, 0, NH);
  k_rope_q2<<<dim3(32, NKV), 256, 0, stream>>>(QKV, ropetab, kph, kpl, 2048, NKV);
  k_split_v2<<<dim3(32, NKV), 256, 0, stream>>>(QKV, vph, vpl);
  k_attn<<<dim3(NH, S_LEN / 128), 256, 0, stream>>>(qph, qpl, kph, kpl, vph, vpl, sinks, aoh, aol);
  k_gemm2<false><<<dim3(2048 / 128, 2048 / 128), 256, 0, stream>>>(aoh, aol, Woh, Wol, bo, out,
                                                                   2048, 2048, 2048);
}

// Round 5
// 293.517 us; speedup vs baseline: 1.1708x; 1.0391x over previous
//
#include <hip/hip_runtime.h>
#include <hip/hip_bf16.h>
#include <stdint.h>

typedef unsigned short u16;
typedef unsigned int   u32;

#define S_LEN 2048
#define NQKV  3072
#define NH    32
#define NKV   8
#define SWIN  128
#define NEGV  (-1.0e9f)
#define SCALE_Q 0.35355339059327379f   // 64^-0.25

typedef __attribute__((ext_vector_type(4)))  float  f32x4;
typedef __attribute__((ext_vector_type(16))) float  f32x16;
typedef __attribute__((ext_vector_type(8)))  __bf16 bf16x8;

__device__ __forceinline__ u16 f2bf(float x){
  u32 u = __float_as_uint(x);
  return (u16)((u + 0x7fffu + ((u >> 16) & 1u)) >> 16);   // RNE
}
__device__ __forceinline__ float bf2f(u16 h){
  return __uint_as_float(((u32)h) << 16);
}
__device__ __forceinline__ void split2(float a, float b, u32& hw, u32& lw){
  u16 ha = f2bf(a), hb = f2bf(b);
  u16 la = f2bf(a - bf2f(ha)), lb = f2bf(b - bf2f(hb));
  hw = (u32)ha | ((u32)hb << 16);
  lw = (u32)la | ((u32)lb << 16);
}
__device__ __forceinline__ f32x4 mfma16(bf16x8 a, bf16x8 b, f32x4 c){
  return __builtin_amdgcn_mfma_f32_16x16x32_bf16(a, b, c, 0, 0, 0);
}
__device__ __forceinline__ f32x16 mfma32(bf16x8 a, bf16x8 b, f32x16 c){
  return __builtin_amdgcn_mfma_f32_32x32x16_bf16(a, b, c, 0, 0, 0);
}

typedef __attribute__((address_space(1))) const unsigned int ga_u32;
typedef __attribute__((address_space(3))) unsigned int       ls_u32;
__device__ __forceinline__ void gl16(const void* g, void* l){
  // direct global->LDS, 16B per lane; LDS dest = wave-uniform base + lane*16
  __builtin_amdgcn_global_load_lds((ga_u32*)g, (ls_u32*)l, 16, 0, 0);
}

// ---------------- prep: rope table [S][32][(cos,sin)] + packed bias[3072] ----
__global__ __launch_bounds__(256) void k_prep(const float* __restrict__ bq,
                                              const float* __restrict__ bk,
                                              const float* __restrict__ bv,
                                              float* __restrict__ ropetab,
                                              float* __restrict__ bias3){
  int id = blockIdx.x * 256 + threadIdx.x;        // S*32 threads
  int t = id >> 5, i = id & 31;
  float e = (i * 2.0f) / 64.0f;
  float base = (float)pow(150000.0, (double)e);
  float invf = 1.0f / base;
  float fr = (float)t * invf;
  ropetab[(size_t)id * 2 + 0] = cosf(fr);
  ropetab[(size_t)id * 2 + 1] = sinf(fr);
  if (id < NQKV){
    float b;
    if (id < 2048) b = bq[id];
    else if (id < 2560) b = bk[id - 2048];
    else b = bv[id - 2560];
    bias3[id] = b;
  }
}

// ---- pack A streaming: fp32 row-major -> hi/lo bf16 [M][K/8][8], SWIZZLED ---
// granule (r,p) stored at p' = (p&~3) | ((p&3) ^ ((r>>1)&3)).  Bijective within
// each aligned 4-packet group (same 64B line -> coalescing preserved).  The
// GEMM's LDS read applies the same XOR -> conflict-free ds_read_b128.
__global__ __launch_bounds__(256) void k_pack_a(const float* __restrict__ in,
                                                u16* __restrict__ oh, u16* __restrict__ ol,
                                                int n8){
  int id = blockIdx.x * 256 + threadIdx.x;
  if (id >= n8) return;
  int r = id >> 8, p = id & 255;              // P = 256 packets per row
  const float4* src = (const float4*)(in + (size_t)id * 8);
  float4 v0 = src[0], v1 = src[1];
  u32 hw[4], lw[4];
  split2(v0.x, v0.y, hw[0], lw[0]);
  split2(v0.z, v0.w, hw[1], lw[1]);
  split2(v1.x, v1.y, hw[2], lw[2]);
  split2(v1.z, v1.w, hw[3], lw[3]);
  int psw = (p & ~3) | ((p & 3) ^ ((r >> 1) & 3));
  size_t o = ((size_t)r * 256 + psw) * 8;
  *(uint4*)(oh + o) = make_uint4(hw[0], hw[1], hw[2], hw[3]);
  *(uint4*)(ol + o) = make_uint4(lw[0], lw[1], lw[2], lw[3]);
}

// ---------------- pack W: fp32 [K][N] (N contig) -> [K/8][NTot][8] at nOff ---
__global__ __launch_bounds__(256) void k_pack_w(const float* __restrict__ w,
                                                u16* __restrict__ oh, u16* __restrict__ ol,
                                                int K, int N, int NTot, int nOff){
  int id = blockIdx.x * 256 + threadIdx.x;
  int P = K >> 3;
  if (id >= P * N) return;
  int p = id / N, n = id % N;
  u32 hw[4], lw[4];
  #pragma unroll
  for (int j = 0; j < 4; ++j){
    float a = w[(size_t)(8 * p + 2 * j) * N + n];
    float b = w[(size_t)(8 * p + 2 * j + 1) * N + n];
    split2(a, b, hw[j], lw[j]);
  }
  size_t o = ((size_t)p * NTot + nOff + n) * 8;
  *(uint4*)(oh + o) = make_uint4(hw[0], hw[1], hw[2], hw[3]);
  *(uint4*)(ol + o) = make_uint4(lw[0], lw[1], lw[2], lw[3]);
}

// ---------------- split-bf16 GEMM v2: dbuf + global_load_lds, 2-phase -------
// ARM=true : A packed [M][K/8][8], source-swizzled (see k_pack_a)
// ARM=false: A packed [K/8][M][8] (attn-output layout, conflict-free natively)
// B packed [K/8][N][8]. 128x128 tile, BK=32, 4 waves (2x2), 16x16x32 MFMA,
// 3 split terms.  T1 XCD-chunked block swizzle (grid total % 8 == 0 required).
template<bool ARM>
__global__ __launch_bounds__(256, 2) void k_gemm2(const u16* __restrict__ Ah, const u16* __restrict__ Al,
                                                  const u16* __restrict__ Bh, const u16* __restrict__ Bl,
                                                  const float* __restrict__ bias, float* __restrict__ C,
                                                  int M, int N, int K){
  __shared__ u16 lds[2][4][512][8];   // 64 KiB: [buf][tensor Ah,Al,Bh,Bl][granule][8]
  const int tid = threadIdx.x;
  const int lane = tid & 63, wid = tid >> 6;
  const int q = lane & 15, g = lane >> 4;
  // T1: XCD-chunked bijective remap of linear block id (totals are %8==0)
  const int nwg = gridDim.x * gridDim.y;
  const int lin = blockIdx.y * gridDim.x + blockIdx.x;
  const int swz = (lin & 7) * (nwg >> 3) + (lin >> 3);
  const int bx = swz % gridDim.x, by = swz / gridDim.x;
  const int m0 = by * 128, n0 = bx * 128;
  const int wr = wid >> 1, wc = wid & 1;
  const int pkK = K >> 3;

  f32x4 acc[4][4];
  #pragma unroll
  for (int a = 0; a < 4; ++a)
    #pragma unroll
    for (int b = 0; b < 4; ++b)
      #pragma unroll
      for (int r = 0; r < 4; ++r) acc[a][b][r] = 0.0f;

  size_t aoff[2], boff[2];
  #pragma unroll
  for (int c = 0; c < 2; ++c){
    int L = c * 256 + tid;
    if (ARM){
      int row = L >> 2, pa = L & 3;
      aoff[c] = ((size_t)(m0 + row) * pkK + pa) * 8;
    } else {
      int pa = L >> 7, row = L & 127;
      aoff[c] = ((size_t)pa * M + m0 + row) * 8;
    }
    int pb = L >> 7, col = L & 127;
    boff[c] = ((size_t)pb * N + n0 + col) * 8;
  }
  const size_t astep = ARM ? (size_t)32 : (size_t)32 * M;   // +4 packets per K-step
  const size_t bstep = (size_t)32 * N;

  const int NT = K >> 5;
  int buf = 0;

  auto STAGE = [&](int b){
    #pragma unroll
    for (int c = 0; c < 2; ++c){
      int lbase = c * 256 + wid * 64;   // wave-uniform LDS granule base
      gl16(Ah + aoff[c], &lds[b][0][lbase][0]);
      gl16(Al + aoff[c], &lds[b][1][lbase][0]);
      gl16(Bh + boff[c], &lds[b][2][lbase][0]);
      gl16(Bl + boff[c], &lds[b][3][lbase][0]);
    }
    aoff[0] += astep; aoff[1] += astep;
    boff[0] += bstep; boff[1] += bstep;
  };

  STAGE(0);
  __syncthreads();

  for (int t = 0; t < NT; ++t){
    if (t + 1 < NT) STAGE(buf ^ 1);   // issue-early: latency hides under MFMA
    bf16x8 ah[4], al[4], bh[4], bl[4];
    #pragma unroll
    for (int ms = 0; ms < 4; ++ms){
      int row = wr * 64 + ms * 16 + q;
      // ARM=true: read-side XOR matches k_pack_a's source swizzle -> 2-way (free)
      int ia = ARM ? (row * 4 + (g ^ ((row >> 1) & 3))) : (g * 128 + row);
      ah[ms] = *(const bf16x8*)&lds[buf][0][ia][0];
      al[ms] = *(const bf16x8*)&lds[buf][1][ia][0];
    }
    #pragma unroll
    for (int ns = 0; ns < 4; ++ns){
      int col = wc * 64 + ns * 16 + q;
      int ib = g * 128 + col;
      bh[ns] = *(const bf16x8*)&lds[buf][2][ib][0];
      bl[ns] = *(const bf16x8*)&lds[buf][3][ib][0];
    }
    #pragma unroll
    for (int ms = 0; ms < 4; ++ms)
      #pragma unroll
      for (int ns = 0; ns < 4; ++ns){
        f32x4 tt = acc[ms][ns];
        tt = mfma16(ah[ms], bh[ns], tt);   // hi*hi
        tt = mfma16(ah[ms], bl[ns], tt);   // hi*lo
        tt = mfma16(al[ms], bh[ns], tt);   // lo*hi
        acc[ms][ns] = tt;
      }
    __syncthreads();   // drains vmcnt+lgkmcnt: next buf ready, this buf free
    buf ^= 1;
  }

  #pragma unroll
  for (int ns = 0; ns < 4; ++ns){
    int col = n0 + wc * 64 + ns * 16 + q;
    float bb = bias[col];
    #pragma unroll
    for (int ms = 0; ms < 4; ++ms){
      int row = m0 + wr * 64 + ms * 16 + g * 4;
      #pragma unroll
      for (int r = 0; r < 4; ++r)
        C[(size_t)(row + r) * N + col] = acc[ms][ns][r] + bb;
    }
  }
}

// -------- fused RoPE+scale+split for q AND k: out [h*8][S][8] hi/lo ---------
// grid (S/64, NH+NKV): blockIdx.y < NH -> q head; else k head
__global__ __launch_bounds__(256) void k_rope(const float* __restrict__ qkv,
                                              const float* __restrict__ tab,
                                              u16* __restrict__ qoh, u16* __restrict__ qol,
                                              u16* __restrict__ koh, u16* __restrict__ kol){
  const int sL = threadIdx.x & 63, tp = threadIdx.x >> 6;
  const int s = blockIdx.x * 64 + sL;
  int h = blockIdx.y;
  u16* oh; u16* ol; int srcOff;
  if (h < NH){ oh = qoh; ol = qol; srcOff = h * 64; }
  else       { h -= NH; oh = koh; ol = kol; srcOff = 2048 + h * 64; }
  const float4* src = (const float4*)(qkv + (size_t)s * NQKV + srcOff + tp * 16);
  const float4* tb  = (const float4*)(tab + (size_t)s * 64 + tp * 16);
  float xv[16], tv[16];
  #pragma unroll
  for (int i = 0; i < 4; ++i){
    float4 a = src[i]; float4 b = tb[i];
    xv[4*i+0]=a.x; xv[4*i+1]=a.y; xv[4*i+2]=a.z; xv[4*i+3]=a.w;
    tv[4*i+0]=b.x; tv[4*i+1]=b.y; tv[4*i+2]=b.z; tv[4*i+3]=b.w;
  }
  u32 hw[8], lw[8];
  #pragma unroll
  for (int j = 0; j < 8; ++j){
    float e = xv[2*j], o = xv[2*j+1];
    float c = tv[2*j], sn = tv[2*j+1];
    float f0 = (e * c - o * sn) * SCALE_Q;
    float f1 = (o * c + e * sn) * SCALE_Q;
    split2(f0, f1, hw[j], lw[j]);
  }
  size_t o0 = ((size_t)(h * 8 + tp * 2 + 0) * S_LEN + s) * 8;
  size_t o1 = ((size_t)(h * 8 + tp * 2 + 1) * S_LEN + s) * 8;
  *(uint4*)(oh + o0) = make_uint4(hw[0], hw[1], hw[2], hw[3]);
  *(uint4*)(oh + o1) = make_uint4(hw[4], hw[5], hw[6], hw[7]);
  *(uint4*)(ol + o0) = make_uint4(lw[0], lw[1], lw[2], lw[3]);
  *(uint4*)(ol + o1) = make_uint4(lw[4], lw[5], lw[6], lw[7]);
}

// ---------------- split V transposed: out [NKV][S/8][64][8], LDS-bounced ----
// grid (S/64, NKV)
__global__ __launch_bounds__(256) void k_split_v2(const float* __restrict__ qkv,
                                                  u16* __restrict__ oh, u16* __restrict__ ol){
  __shared__ float tile[64][65];
  const int h = blockIdx.y;
  const int s0 = blockIdx.x * 64;
  {
    const int sL = threadIdx.x >> 2, ch = threadIdx.x & 3;
    const float4* rp = (const float4*)(qkv + (size_t)(s0 + sL) * NQKV + 2560 + h * 64 + ch * 16);
    #pragma unroll
    for (int i = 0; i < 4; ++i){
      float4 w = rp[i];
      tile[sL][ch * 16 + i * 4 + 0] = w.x;
      tile[sL][ch * 16 + i * 4 + 1] = w.y;
      tile[sL][ch * 16 + i * 4 + 2] = w.z;
      tile[sL][ch * 16 + i * 4 + 3] = w.w;
    }
  }
  __syncthreads();
  const int d = threadIdx.x & 63, spg = threadIdx.x >> 6;
  #pragma unroll
  for (int sp2 = 0; sp2 < 2; ++sp2){
    int spl = spg * 2 + sp2;
    float v[8];
    #pragma unroll
    for (int j = 0; j < 8; ++j) v[j] = tile[spl * 8 + j][d];
    u32 hw[4], lw[4];
    #pragma unroll
    for (int j = 0; j < 4; ++j) split2(v[2*j], v[2*j+1], hw[j], lw[j]);
    size_t o_ = (((size_t)h * 256 + blockIdx.x * 8 + spl) * 64 + d) * 8;
    *(uint4*)(oh + o_) = make_uint4(hw[0], hw[1], hw[2], hw[3]);
    *(uint4*)(ol + o_) = make_uint4(lw[0], lw[1], lw[2], lw[3]);
  }
}

// ---------------- banded attention with sink (flash, swapped QK^T) ----------
__global__ __launch_bounds__(256) void k_attn(const u16* __restrict__ qh, const u16* __restrict__ ql,
                                              const u16* __restrict__ kh, const u16* __restrict__ kl,
                                              const u16* __restrict__ vh, const u16* __restrict__ vl,
                                              const float* __restrict__ sinks,
                                              u16* __restrict__ aoh, u16* __restrict__ aol){
  const int lane = threadIdx.x & 63;
  const int wid = threadIdx.x >> 6;
  const int h = blockIdx.x;
  const int hkv = h >> 2;
  const int q0 = blockIdx.y * 128 + wid * 32;
  const int lq = lane & 31;
  const int half = lane >> 5;
  const int qi = q0 + lq;

  bf16x8 qfh[4], qfl[4];
  #pragma unroll
  for (int st = 0; st < 4; ++st){
    size_t off = (((size_t)h * 8 + st * 2 + half) * S_LEN + qi) * 8;
    qfh[st] = *(const bf16x8*)(qh + off);
    qfl[st] = *(const bf16x8*)(ql + off);
  }
  float m = sinks[h];
  float lsum = 1.0f;
  f32x16 o0, o1;
  #pragma unroll
  for (int r = 0; r < 16; ++r){ o0[r] = 0.0f; o1[r] = 0.0f; }

  const int kb0 = q0 - 128;
  for (int c = 0; c < 9; ++c){
    const int kb = kb0 + c * 32;
    if (kb + 32 <= 0 || kb >= S_LEN) continue;
    const int keyr = kb + lq;
    const int keyc = min(max(keyr, 0), S_LEN - 1);
    f32x16 sc;
    #pragma unroll
    for (int r = 0; r < 16; ++r) sc[r] = 0.0f;
    #pragma unroll
    for (int st = 0; st < 4; ++st){
      size_t ko = (((size_t)hkv * 8 + st * 2 + half) * S_LEN + keyc) * 8;
      bf16x8 kfh = *(const bf16x8*)(kh + ko);
      bf16x8 kfl = *(const bf16x8*)(kl + ko);
      sc = mfma32(kfh, qfh[st], sc);
      sc = mfma32(kfh, qfl[st], sc);
      sc = mfma32(kfl, qfh[st], sc);
    }
    float tmax = -3.0e38f;
    #pragma unroll
    for (int r = 0; r < 16; ++r){
      int key = kb + (r & 3) + 8 * (r >> 2) + 4 * half;
      int dd = qi - key; if (dd < 0) dd = -dd;
      bool ok = (key >= 0) && (key < S_LEN) && (dd <= SWIN);
      sc[r] = ok ? sc[r] : NEGV;
      tmax = fmaxf(tmax, sc[r]);
    }
    tmax = fmaxf(tmax, __shfl_xor(tmax, 32));
    float mn = fmaxf(m, tmax);
    float alpha = __expf(m - mn);
    m = mn;
    float p[16]; float ps = 0.0f;
    #pragma unroll
    for (int r = 0; r < 16; ++r){ p[r] = __expf(sc[r] - mn); ps += p[r]; }
    ps += __shfl_xor(ps, 32);
    lsum = lsum * alpha + ps;
    #pragma unroll
    for (int r = 0; r < 16; ++r){ o0[r] *= alpha; o1[r] *= alpha; }
    u32 wh[8], wl[8];
    #pragma unroll
    for (int j = 0; j < 8; ++j) split2(p[2 * j], p[2 * j + 1], wh[j], wl[j]);
    bf16x8 pfh[2], pfl[2];
    #pragma unroll
    for (int ks = 0; ks < 2; ++ks){
      u32 x0 = wh[4 * ks + 0], y0 = wh[4 * ks + 2];
      u32 x1 = wh[4 * ks + 1], y1 = wh[4 * ks + 3];
      u32 sx0 = __shfl_xor(x0, 32), sy0 = __shfl_xor(y0, 32);
      u32 sx1 = __shfl_xor(x1, 32), sy1 = __shfl_xor(y1, 32);
      union { u32 u[4]; bf16x8 b; } fb;
      fb.u[0] = half ? sy0 : x0;
      fb.u[1] = half ? sy1 : x1;
      fb.u[2] = half ? y0 : sx0;
      fb.u[3] = half ? y1 : sx1;
      pfh[ks] = fb.b;
      u32 a0 = wl[4 * ks + 0], b0 = wl[4 * ks + 2];
      u32 a1 = wl[4 * ks + 1], b1 = wl[4 * ks + 3];
      u32 sa0 = __shfl_xor(a0, 32), sb0 = __shfl_xor(b0, 32);
      u32 sa1 = __shfl_xor(a1, 32), sb1 = __shfl_xor(b1, 32);
      fb.u[0] = half ? sb0 : a0;
      fb.u[1] = half ? sb1 : a1;
      fb.u[2] = half ? b0 : sa0;
      fb.u[3] = half ? b1 : sa1;
      pfl[ks] = fb.b;
    }
    #pragma unroll
    for (int ks = 0; ks < 2; ++ks){
      int kp = kb / 8 + ks * 2 + half;
      kp = min(max(kp, 0), S_LEN / 8 - 1);
      #pragma unroll
      for (int nt = 0; nt < 2; ++nt){
        size_t vo = (((size_t)hkv * 256 + kp) * 64 + nt * 32 + lq) * 8;
        bf16x8 vfh = *(const bf16x8*)(vh + vo);
        bf16x8 vfl = *(const bf16x8*)(vl + vo);
        f32x16 acc = (nt == 0) ? o0 : o1;
        acc = mfma32(vfh, pfh[ks], acc);
        acc = mfma32(vfh, pfl[ks], acc);
        acc = mfma32(vfl, pfh[ks], acc);
        if (nt == 0) o0 = acc; else o1 = acc;
      }
    }
  }
  float inv = 1.0f / lsum;
  #pragma unroll
  for (int nt = 0; nt < 2; ++nt){
    f32x16 o = (nt == 0) ? o0 : o1;
    #pragma unroll
    for (int rr = 0; rr < 4; ++rr){
      int d0 = nt * 32 + 8 * rr + 4 * half;
      u32 hw0, hw1, lw0, lw1;
      float v0 = o[rr * 4 + 0] * inv, v1 = o[rr * 4 + 1] * inv;
      float v2 = o[rr * 4 + 2] * inv, v3 = o[rr * 4 + 3] * inv;
      split2(v0, v1, hw0, lw0);
      split2(v2, v3, hw1, lw1);
      int kp_ = h * 8 + nt * 4 + rr;
      size_t oo = ((size_t)kp_ * S_LEN + qi) * 8 + (d0 & 7);
      uint2 wv; wv.x = hw0; wv.y = hw1;
      *(uint2*)(aoh + oo) = wv;
      wv.x = lw0; wv.y = lw1;
      *(uint2*)(aol + oo) = wv;
    }
  }
}

// ---------------------------------------------------------------------------
extern "C" void kernel_launch(void* const* d_in, const int* in_sizes, int n_in,
                              void* d_out, int out_size, void* d_ws, size_t ws_size,
                              hipStream_t stream){
  const float* hid = (const float*)d_in[0];
  const float* Wq  = (const float*)d_in[1];
  const float* bq  = (const float*)d_in[2];
  const float* Wk  = (const float*)d_in[3];
  const float* bk  = (const float*)d_in[4];
  const float* Wv  = (const float*)d_in[5];
  const float* bv  = (const float*)d_in[6];
  const float* Wo  = (const float*)d_in[7];
  const float* bo  = (const float*)d_in[8];
  const float* sinks = (const float*)d_in[9];
  float* out = (float*)d_out;

  char* w = (char*)d_ws;
  size_t off = 0;
  auto alloc = [&](size_t bytes){ void* p = w + off; off += (bytes + 255) & ~(size_t)255; return p; };
  float* ropetab = (float*)alloc((size_t)S_LEN * 32 * 2 * 4);
  float* bias3   = (float*)alloc((size_t)NQKV * 4);
  u16* Ah  = (u16*)alloc((size_t)2048 * 2048 * 2);        // hidden packed [M][K/8][8] swz
  u16* Al  = (u16*)alloc((size_t)2048 * 2048 * 2);
  u16* Bh  = (u16*)alloc((size_t)256 * NQKV * 8 * 2);     // Wq|Wk|Wv packed [K/8][N][8]
  u16* Bl  = (u16*)alloc((size_t)256 * NQKV * 8 * 2);
  float* QKV = (float*)alloc((size_t)S_LEN * NQKV * 4);
  u16* qph = (u16*)alloc((size_t)NH * 8 * S_LEN * 8 * 2);
  u16* qpl = (u16*)alloc((size_t)NH * 8 * S_LEN * 8 * 2);
  u16* kph = (u16*)alloc((size_t)NKV * 8 * S_LEN * 8 * 2);
  u16* kpl = (u16*)alloc((size_t)NKV * 8 * S_LEN * 8 * 2);
  u16* vph = (u16*)alloc((size_t)NKV * 256 * 64 * 8 * 2);
  u16* vpl = (u16*)alloc((size_t)NKV * 256 * 64 * 8 * 2);
  u16* aoh = (u16*)alloc((size_t)256 * S_LEN * 8 * 2);    // attn out [K/8][S][8]
  u16* aol = (u16*)alloc((size_t)256 * S_LEN * 8 * 2);
  u16* Woh = (u16*)alloc((size_t)256 * 2048 * 8 * 2);
  u16* Wol = (u16*)alloc((size_t)256 * 2048 * 8 * 2);
  (void)in_sizes; (void)n_in; (void)out_size; (void)ws_size;

  k_prep<<<256, 256, 0, stream>>>(bq, bk, bv, ropetab, bias3);
  k_pack_a<<<2048, 256, 0, stream>>>(hid, Ah, Al, 2048 * 256);
  k_pack_w<<<2048, 256, 0, stream>>>(Wq, Bh, Bl, 2048, 2048, NQKV, 0);
  k_pack_w<<<512, 256, 0, stream>>>(Wk, Bh, Bl, 2048, 512, NQKV, 2048);
  k_pack_w<<<512, 256, 0, stream>>>(Wv, Bh, Bl, 2048, 512, NQKV, 2560);
  k_pack_w<<<2048, 256, 0, stream>>>(Wo, Woh, Wol, 2048, 2048, 2048, 0);
  k_gemm2<true><<<dim3(NQKV / 128, 2048 / 128), 256, 0, stream>>>(Ah, Al, Bh, Bl, bias3, QKV,
                                                                  2048, NQKV, 2048);
  k_rope<<<dim3(32, NH + NKV), 256, 0, stream>>>(QKV, ropetab, qph, qpl, kph, kpl);
  k_split_v2<<<dim3(32, NKV), 256, 0, stream>>>(QKV, vph, vpl);
  k_attn<<<dim3(NH, S_LEN / 128), 256, 0, stream>>>(qph, qpl, kph, kpl, vph, vpl, sinks, aoh, aol);
  k_gemm2<false><<<dim3(2048 / 128, 2048 / 128), 256, 0, stream>>>(aoh, aol, Woh, Wol, bo, out,
                                                                   2048, 2048, 2048);
}